// Round 1
// baseline (1171.427 us; speedup 1.0000x reference)
//
#include <hip/hip_runtime.h>
#include <hip/hip_bf16.h>

#define N_NODES 50000
#define E_EDGES 500000
#define HID 128
#define NHEAD 4
#define HDIM 32

// ---------------------------------------------------------------------------
// FiLM: film[j] = task @ W_film[:,j] + b_film[j]; store gamma-factor and beta
// ---------------------------------------------------------------------------
__global__ __launch_bounds__(256) void film_kernel(
    const float* __restrict__ task, const float* __restrict__ Wf,
    const float* __restrict__ bf, float* __restrict__ film)
{
    __shared__ float tsk[HID];
    const int t = threadIdx.x;
    if (t < HID) tsk[t] = task[t];
    __syncthreads();
    float acc = bf[t];
    #pragma unroll 8
    for (int k = 0; k < HID; ++k)
        acc = fmaf(tsk[k], Wf[k * 256 + t], acc);
    if (t < HID) film[t] = 1.f + 0.5f * tanhf(acc);   // gamma factor
    else         film[t] = acc;                        // beta
}

// ---------------------------------------------------------------------------
// Fused x_src / x_dst GEMM: [32 nodes] x [256 cols (128 src | 128 dst)]
// 256 threads: tx = lane (64 col-groups of 4), ty = wave (4 groups of 8 nodes)
// A tile staged in LDS; reads are wave-uniform broadcasts (conflict-free).
// ---------------------------------------------------------------------------
__global__ __launch_bounds__(256) void gemm_srcdst(
    const float* __restrict__ A,
    const float* __restrict__ Ws, const float* __restrict__ bs,
    const float* __restrict__ Wd, const float* __restrict__ bd,
    float* __restrict__ xs, float* __restrict__ xd)
{
    __shared__ float a_tile[32][HID];
    const int t  = threadIdx.x;
    const int nb = blockIdx.x * 32;

    #pragma unroll
    for (int i = 0; i < 4; ++i) {
        int f  = t + 256 * i;        // float4 index within tile
        int m  = f >> 5;             // node within tile (32 float4 per row)
        int k4 = f & 31;
        int node = nb + m;
        float4 v;
        if (node < N_NODES) v = *(const float4*)(A + (size_t)node * HID + k4 * 4);
        else { v.x = v.y = v.z = v.w = 0.f; }
        *(float4*)&a_tile[m][k4 * 4] = v;
    }
    __syncthreads();

    const int tx = t & 63;
    const int ty = t >> 6;            // wave id (uniform within wave)
    const int m0 = ty * 8;
    const bool is_src = (tx < 32);
    const int cc = (tx & 31) * 4;
    const float* W    = is_src ? Ws : Wd;
    const float* bias = is_src ? bs : bd;
    float*       xout = is_src ? xs : xd;

    float acc[8][4];
    #pragma unroll
    for (int m = 0; m < 8; ++m)
        #pragma unroll
        for (int j = 0; j < 4; ++j) acc[m][j] = 0.f;

    for (int kc = 0; kc < 32; ++kc) {
        const int k0 = kc * 4;
        const float4 w0 = *(const float4*)(W + (size_t)(k0 + 0) * HID + cc);
        const float4 w1 = *(const float4*)(W + (size_t)(k0 + 1) * HID + cc);
        const float4 w2 = *(const float4*)(W + (size_t)(k0 + 2) * HID + cc);
        const float4 w3 = *(const float4*)(W + (size_t)(k0 + 3) * HID + cc);
        #pragma unroll
        for (int m = 0; m < 8; ++m) {
            const float4 av = *(const float4*)&a_tile[m0 + m][k0];
            acc[m][0] = fmaf(av.x, w0.x, acc[m][0]);
            acc[m][1] = fmaf(av.x, w0.y, acc[m][1]);
            acc[m][2] = fmaf(av.x, w0.z, acc[m][2]);
            acc[m][3] = fmaf(av.x, w0.w, acc[m][3]);
            acc[m][0] = fmaf(av.y, w1.x, acc[m][0]);
            acc[m][1] = fmaf(av.y, w1.y, acc[m][1]);
            acc[m][2] = fmaf(av.y, w1.z, acc[m][2]);
            acc[m][3] = fmaf(av.y, w1.w, acc[m][3]);
            acc[m][0] = fmaf(av.z, w2.x, acc[m][0]);
            acc[m][1] = fmaf(av.z, w2.y, acc[m][1]);
            acc[m][2] = fmaf(av.z, w2.z, acc[m][2]);
            acc[m][3] = fmaf(av.z, w2.w, acc[m][3]);
            acc[m][0] = fmaf(av.w, w3.x, acc[m][0]);
            acc[m][1] = fmaf(av.w, w3.y, acc[m][1]);
            acc[m][2] = fmaf(av.w, w3.z, acc[m][2]);
            acc[m][3] = fmaf(av.w, w3.w, acc[m][3]);
        }
    }

    const float4 bv = *(const float4*)(bias + cc);
    #pragma unroll
    for (int m = 0; m < 8; ++m) {
        const int node = nb + m0 + m;
        if (node < N_NODES) {
            float4 o;
            o.x = acc[m][0] + bv.x;
            o.y = acc[m][1] + bv.y;
            o.z = acc[m][2] + bv.z;
            o.w = acc[m][3] + bv.w;
            *(float4*)(xout + (size_t)node * HID + cc) = o;
        }
    }
}

// ---------------------------------------------------------------------------
// Edge pass: 32 lanes per edge. Computes per-head logit, ex = exp(logit),
// scatters ex into sums[dst,h] and ex*x_src into agg[dst,:].
// (max-subtraction dropped: softmax is shift-invariant, logits are O(1..8))
// ---------------------------------------------------------------------------
__global__ __launch_bounds__(256) void edge_pass(
    const int* __restrict__ ei, const int* __restrict__ et,
    const float* __restrict__ xsrc, const float* __restrict__ xdst,
    const float* __restrict__ eemb, const float* __restrict__ att,
    float* __restrict__ sums, float* __restrict__ agg)
{
    const int lane = threadIdx.x & 31;
    const int grp  = threadIdx.x >> 5;      // 8 edge-groups per block
    const float4 av = *(const float4*)(att + lane * 4);
    const int stride = gridDim.x * 8;
    for (int e = blockIdx.x * 8 + grp; e < E_EDGES; e += stride) {
        const int s  = ei[e];
        const int d  = ei[E_EDGES + e];
        const int ty = et[e];
        const float4 xs = *(const float4*)(xsrc + (size_t)s * HID + lane * 4);
        const float4 xd = *(const float4*)(xdst + (size_t)d * HID + lane * 4);
        const float4 ev = *(const float4*)(eemb + (size_t)ty * HID + lane * 4);
        float c, p = 0.f;
        c = xs.x + xd.x + ev.x; c = (c > 0.f) ? c : 0.2f * c; p = fmaf(c, av.x, p);
        c = xs.y + xd.y + ev.y; c = (c > 0.f) ? c : 0.2f * c; p = fmaf(c, av.y, p);
        c = xs.z + xd.z + ev.z; c = (c > 0.f) ? c : 0.2f * c; p = fmaf(c, av.z, p);
        c = xs.w + xd.w + ev.w; c = (c > 0.f) ? c : 0.2f * c; p = fmaf(c, av.w, p);
        // reduce across the 8 lanes of this head
        p += __shfl_xor(p, 1);
        p += __shfl_xor(p, 2);
        p += __shfl_xor(p, 4);
        const float ex = expf(p);
        if ((lane & 7) == 0)
            unsafeAtomicAdd(sums + (size_t)d * NHEAD + (lane >> 3), ex);
        float* ag = agg + (size_t)d * HID + lane * 4;
        unsafeAtomicAdd(ag + 0, ex * xs.x);
        unsafeAtomicAdd(ag + 1, ex * xs.y);
        unsafeAtomicAdd(ag + 2, ex * xs.z);
        unsafeAtomicAdd(ag + 3, ex * xs.w);
    }
}

// ---------------------------------------------------------------------------
// Finalize: per node — normalize agg by sums, @ W_out + b_out, FiLM,
// residual, LayerNorm. 128 threads (2 waves) per block, 8 nodes per block.
// ---------------------------------------------------------------------------
__global__ __launch_bounds__(128) void finalize(
    const float* __restrict__ agg, const float* __restrict__ sums,
    const float* __restrict__ A,   const float* __restrict__ Wo,
    const float* __restrict__ bo,  const float* __restrict__ film,
    const float* __restrict__ nw_, const float* __restrict__ nb_,
    float* __restrict__ out)
{
    __shared__ float vals[8][HID];
    __shared__ float red[2][2];
    const int t  = threadIdx.x;
    const int nb = blockIdx.x * 8;

    #pragma unroll
    for (int m = 0; m < 8; ++m) {
        const int node = nb + m;
        float v = 0.f;
        if (node < N_NODES) {
            const float s = sums[(size_t)node * NHEAD + (t >> 5)];
            v = agg[(size_t)node * HID + t] / fmaxf(s, 1e-12f);
        }
        vals[m][t] = v;
    }
    __syncthreads();

    const float gf  = film[t];
    const float bt  = film[HID + t];
    const float bov = bo[t];
    const float nwv = nw_[t];
    const float nbv = nb_[t];
    const int wave = t >> 6;
    const int lane = t & 63;

    for (int m = 0; m < 8; ++m) {
        const int node = nb + m;
        float acc = 0.f;
        #pragma unroll
        for (int k = 0; k < HID; k += 4) {
            const float4 v4 = *(const float4*)&vals[m][k];   // broadcast
            acc = fmaf(v4.x, Wo[(size_t)(k + 0) * HID + t], acc);
            acc = fmaf(v4.y, Wo[(size_t)(k + 1) * HID + t], acc);
            acc = fmaf(v4.z, Wo[(size_t)(k + 2) * HID + t], acc);
            acc = fmaf(v4.w, Wo[(size_t)(k + 3) * HID + t], acc);
        }
        float v = acc + bov;
        v = v * gf + bt;                                    // FiLM
        const float y = (node < N_NODES ? A[(size_t)node * HID + t] : 0.f) + v;

        float s1 = y, s2 = y * y;
        #pragma unroll
        for (int off = 32; off; off >>= 1) {
            s1 += __shfl_down(s1, off);
            s2 += __shfl_down(s2, off);
        }
        if (lane == 0) { red[wave][0] = s1; red[wave][1] = s2; }
        __syncthreads();
        const float tot1 = red[0][0] + red[1][0];
        const float tot2 = red[0][1] + red[1][1];
        const float mu  = tot1 * (1.f / 128.f);
        const float var = tot2 * (1.f / 128.f) - mu * mu;
        const float rsig = rsqrtf(var + 1e-5f);
        if (node < N_NODES)
            out[(size_t)node * HID + t] = (y - mu) * rsig * nwv + nbv;
        __syncthreads();   // red reused next m
    }
}

// ---------------------------------------------------------------------------
extern "C" void kernel_launch(void* const* d_in, const int* in_sizes, int n_in,
                              void* d_out, int out_size, void* d_ws, size_t ws_size,
                              hipStream_t stream)
{
    const float* node_emb = (const float*)d_in[0];
    const int*   edge_idx = (const int*)  d_in[1];
    const int*   edge_ty  = (const int*)  d_in[2];
    const float* task     = (const float*)d_in[3];
    const float* W_src    = (const float*)d_in[4];
    const float* b_src    = (const float*)d_in[5];
    const float* W_dst    = (const float*)d_in[6];
    const float* b_dst    = (const float*)d_in[7];
    const float* edge_emb = (const float*)d_in[8];
    const float* att      = (const float*)d_in[9];
    const float* W_out    = (const float*)d_in[10];
    const float* b_out    = (const float*)d_in[11];
    const float* norm_w   = (const float*)d_in[12];
    const float* norm_b   = (const float*)d_in[13];
    const float* W_film   = (const float*)d_in[14];
    const float* b_film   = (const float*)d_in[15];
    float* out = (float*)d_out;

    float* ws    = (float*)d_ws;
    float* x_src = ws;                                  // N*128
    float* x_dst = x_src + (size_t)N_NODES * HID;       // N*128
    float* agg   = x_dst + (size_t)N_NODES * HID;       // N*128
    float* sums  = agg   + (size_t)N_NODES * HID;       // N*4
    float* film  = sums  + (size_t)N_NODES * NHEAD;     // 256

    hipMemsetAsync(agg,  0, (size_t)N_NODES * HID * sizeof(float), stream);
    hipMemsetAsync(sums, 0, (size_t)N_NODES * NHEAD * sizeof(float), stream);

    film_kernel<<<1, 256, 0, stream>>>(task, W_film, b_film, film);
    gemm_srcdst<<<(N_NODES + 31) / 32, 256, 0, stream>>>(
        node_emb, W_src, b_src, W_dst, b_dst, x_src, x_dst);
    edge_pass<<<4096, 256, 0, stream>>>(
        edge_idx, edge_ty, x_src, x_dst, edge_emb, att, sums, agg);
    finalize<<<(N_NODES + 7) / 8, 128, 0, stream>>>(
        agg, sums, node_emb, W_out, b_out, film, norm_w, norm_b, out);
}

// Round 2
// 498.749 us; speedup vs baseline: 2.3487x; 2.3487x over previous
//
#include <hip/hip_runtime.h>
#include <hip/hip_bf16.h>

#define N_NODES 50000
#define E_EDGES 500000
#define HID 128
#define NHEAD 4
#define HDIM 32

// ---------------------------------------------------------------------------
// FiLM: film[j] = task @ W_film[:,j] + b_film[j]; store gamma-factor and beta
// ---------------------------------------------------------------------------
__global__ __launch_bounds__(256) void film_kernel(
    const float* __restrict__ task, const float* __restrict__ Wf,
    const float* __restrict__ bf, float* __restrict__ film)
{
    __shared__ float tsk[HID];
    const int t = threadIdx.x;
    if (t < HID) tsk[t] = task[t];
    __syncthreads();
    float acc = bf[t];
    #pragma unroll 8
    for (int k = 0; k < HID; ++k)
        acc = fmaf(tsk[k], Wf[k * 256 + t], acc);
    if (t < HID) film[t] = 1.f + 0.5f * tanhf(acc);   // gamma factor
    else         film[t] = acc;                        // beta
}

// ---------------------------------------------------------------------------
// Fused x_src / x_dst GEMM: [32 nodes] x [256 cols (128 src | 128 dst)]
// ---------------------------------------------------------------------------
__global__ __launch_bounds__(256) void gemm_srcdst(
    const float* __restrict__ A,
    const float* __restrict__ Ws, const float* __restrict__ bs,
    const float* __restrict__ Wd, const float* __restrict__ bd,
    float* __restrict__ xs, float* __restrict__ xd)
{
    __shared__ float a_tile[32][HID];
    const int t  = threadIdx.x;
    const int nb = blockIdx.x * 32;

    #pragma unroll
    for (int i = 0; i < 4; ++i) {
        int f  = t + 256 * i;        // float4 index within tile
        int m  = f >> 5;             // node within tile (32 float4 per row)
        int k4 = f & 31;
        int node = nb + m;
        float4 v;
        if (node < N_NODES) v = *(const float4*)(A + (size_t)node * HID + k4 * 4);
        else { v.x = v.y = v.z = v.w = 0.f; }
        *(float4*)&a_tile[m][k4 * 4] = v;
    }
    __syncthreads();

    const int tx = t & 63;
    const int ty = t >> 6;            // wave id (uniform within wave)
    const int m0 = ty * 8;
    const bool is_src = (tx < 32);
    const int cc = (tx & 31) * 4;
    const float* W    = is_src ? Ws : Wd;
    const float* bias = is_src ? bs : bd;
    float*       xout = is_src ? xs : xd;

    float acc[8][4];
    #pragma unroll
    for (int m = 0; m < 8; ++m)
        #pragma unroll
        for (int j = 0; j < 4; ++j) acc[m][j] = 0.f;

    for (int kc = 0; kc < 32; ++kc) {
        const int k0 = kc * 4;
        const float4 w0 = *(const float4*)(W + (size_t)(k0 + 0) * HID + cc);
        const float4 w1 = *(const float4*)(W + (size_t)(k0 + 1) * HID + cc);
        const float4 w2 = *(const float4*)(W + (size_t)(k0 + 2) * HID + cc);
        const float4 w3 = *(const float4*)(W + (size_t)(k0 + 3) * HID + cc);
        #pragma unroll
        for (int m = 0; m < 8; ++m) {
            const float4 av = *(const float4*)&a_tile[m0 + m][k0];
            acc[m][0] = fmaf(av.x, w0.x, acc[m][0]);
            acc[m][1] = fmaf(av.x, w0.y, acc[m][1]);
            acc[m][2] = fmaf(av.x, w0.z, acc[m][2]);
            acc[m][3] = fmaf(av.x, w0.w, acc[m][3]);
            acc[m][0] = fmaf(av.y, w1.x, acc[m][0]);
            acc[m][1] = fmaf(av.y, w1.y, acc[m][1]);
            acc[m][2] = fmaf(av.y, w1.z, acc[m][2]);
            acc[m][3] = fmaf(av.y, w1.w, acc[m][3]);
            acc[m][0] = fmaf(av.z, w2.x, acc[m][0]);
            acc[m][1] = fmaf(av.z, w2.y, acc[m][1]);
            acc[m][2] = fmaf(av.z, w2.z, acc[m][2]);
            acc[m][3] = fmaf(av.z, w2.w, acc[m][3]);
            acc[m][0] = fmaf(av.w, w3.x, acc[m][0]);
            acc[m][1] = fmaf(av.w, w3.y, acc[m][1]);
            acc[m][2] = fmaf(av.w, w3.z, acc[m][2]);
            acc[m][3] = fmaf(av.w, w3.w, acc[m][3]);
        }
    }

    const float4 bv = *(const float4*)(bias + cc);
    #pragma unroll
    for (int m = 0; m < 8; ++m) {
        const int node = nb + m0 + m;
        if (node < N_NODES) {
            float4 o;
            o.x = acc[m][0] + bv.x;
            o.y = acc[m][1] + bv.y;
            o.z = acc[m][2] + bv.z;
            o.w = acc[m][3] + bv.w;
            *(float4*)(xout + (size_t)node * HID + cc) = o;
        }
    }
}

// ---------------------------------------------------------------------------
// CSR build, step 1: in-degree histogram over dst
// ---------------------------------------------------------------------------
__global__ __launch_bounds__(256) void hist_kernel(
    const int* __restrict__ ei, int* __restrict__ deg)
{
    const int e = blockIdx.x * 256 + threadIdx.x;
    if (e < E_EDGES) atomicAdd(&deg[ei[E_EDGES + e]], 1);
}

// ---------------------------------------------------------------------------
// CSR build, step 2: single-block exclusive scan of deg -> rowptr (+cursor)
// ---------------------------------------------------------------------------
__global__ __launch_bounds__(1024) void scan_kernel(
    const int* __restrict__ deg, int* __restrict__ rowptr, int* __restrict__ cursor)
{
    __shared__ int part[1024];
    const int t = threadIdx.x;
    const int CH = (N_NODES + 1023) / 1024;   // 49
    const int base = t * CH;
    int s = 0;
    for (int i = 0; i < CH; ++i) {
        const int idx = base + i;
        if (idx < N_NODES) s += deg[idx];
    }
    part[t] = s;
    __syncthreads();
    for (int off = 1; off < 1024; off <<= 1) {
        const int v = (t >= off) ? part[t - off] : 0;
        __syncthreads();
        part[t] += v;
        __syncthreads();
    }
    int run = part[t] - s;                    // exclusive prefix for this chunk
    for (int i = 0; i < CH; ++i) {
        const int idx = base + i;
        if (idx < N_NODES) {
            rowptr[idx] = run;
            cursor[idx] = run;
            run += deg[idx];
        }
    }
    if (t == 0) rowptr[N_NODES] = E_EDGES;
}

// ---------------------------------------------------------------------------
// CSR build, step 3: scatter packed (src | etype<<16) records into dst bins
// ---------------------------------------------------------------------------
__global__ __launch_bounds__(256) void scatter_kernel(
    const int* __restrict__ ei, const int* __restrict__ et,
    int* __restrict__ cursor, int* __restrict__ pack)
{
    const int e = blockIdx.x * 256 + threadIdx.x;
    if (e < E_EDGES) {
        const int d = ei[E_EDGES + e];
        const int pos = atomicAdd(&cursor[d], 1);
        pack[pos] = ei[e] | (et[e] << 16);    // src < 65536, etype < 8
    }
}

// ---------------------------------------------------------------------------
// Gather-aggregate: one 32-lane group per dst node. Walks in-edges, computes
// ex = exp(logit), accumulates ex*x_src and ex in registers; normalizes and
// writes one 512B row per node. Zero atomics.
// ---------------------------------------------------------------------------
__global__ __launch_bounds__(256) void gather_agg(
    const int* __restrict__ rowptr, const int* __restrict__ pack,
    const float* __restrict__ xsrc, const float* __restrict__ xdst,
    const float* __restrict__ eemb, const float* __restrict__ att,
    float* __restrict__ agg)
{
    const int lane = threadIdx.x & 31;
    const int grp  = threadIdx.x >> 5;
    const int node = blockIdx.x * 8 + grp;
    if (node >= N_NODES) return;

    const float4 av = *(const float4*)(att + lane * 4);
    const float4 xd = *(const float4*)(xdst + (size_t)node * HID + lane * 4);

    float a0 = 0.f, a1 = 0.f, a2 = 0.f, a3 = 0.f, sum = 0.f;
    const int b = rowptr[node];
    const int e = rowptr[node + 1];

    int i = b;
    for (; i + 1 < e; i += 2) {               // 2-wide for load overlap
        const int pk0 = pack[i];
        const int pk1 = pack[i + 1];
        const int s0 = pk0 & 0xFFFF, ty0 = pk0 >> 16;
        const int s1 = pk1 & 0xFFFF, ty1 = pk1 >> 16;
        const float4 xs0 = *(const float4*)(xsrc + (size_t)s0 * HID + lane * 4);
        const float4 ev0 = *(const float4*)(eemb + (size_t)ty0 * HID + lane * 4);
        const float4 xs1 = *(const float4*)(xsrc + (size_t)s1 * HID + lane * 4);
        const float4 ev1 = *(const float4*)(eemb + (size_t)ty1 * HID + lane * 4);
        float c, p0 = 0.f, p1 = 0.f;
        c = xs0.x + xd.x + ev0.x; c = (c > 0.f) ? c : 0.2f * c; p0 = fmaf(c, av.x, p0);
        c = xs0.y + xd.y + ev0.y; c = (c > 0.f) ? c : 0.2f * c; p0 = fmaf(c, av.y, p0);
        c = xs0.z + xd.z + ev0.z; c = (c > 0.f) ? c : 0.2f * c; p0 = fmaf(c, av.z, p0);
        c = xs0.w + xd.w + ev0.w; c = (c > 0.f) ? c : 0.2f * c; p0 = fmaf(c, av.w, p0);
        c = xs1.x + xd.x + ev1.x; c = (c > 0.f) ? c : 0.2f * c; p1 = fmaf(c, av.x, p1);
        c = xs1.y + xd.y + ev1.y; c = (c > 0.f) ? c : 0.2f * c; p1 = fmaf(c, av.y, p1);
        c = xs1.z + xd.z + ev1.z; c = (c > 0.f) ? c : 0.2f * c; p1 = fmaf(c, av.z, p1);
        c = xs1.w + xd.w + ev1.w; c = (c > 0.f) ? c : 0.2f * c; p1 = fmaf(c, av.w, p1);
        p0 += __shfl_xor(p0, 1); p1 += __shfl_xor(p1, 1);
        p0 += __shfl_xor(p0, 2); p1 += __shfl_xor(p1, 2);
        p0 += __shfl_xor(p0, 4); p1 += __shfl_xor(p1, 4);
        const float ex0 = expf(p0);
        const float ex1 = expf(p1);
        a0 = fmaf(ex0, xs0.x, a0); a1 = fmaf(ex0, xs0.y, a1);
        a2 = fmaf(ex0, xs0.z, a2); a3 = fmaf(ex0, xs0.w, a3);
        a0 = fmaf(ex1, xs1.x, a0); a1 = fmaf(ex1, xs1.y, a1);
        a2 = fmaf(ex1, xs1.z, a2); a3 = fmaf(ex1, xs1.w, a3);
        sum += ex0 + ex1;
    }
    if (i < e) {                              // tail
        const int pk0 = pack[i];
        const int s0 = pk0 & 0xFFFF, ty0 = pk0 >> 16;
        const float4 xs0 = *(const float4*)(xsrc + (size_t)s0 * HID + lane * 4);
        const float4 ev0 = *(const float4*)(eemb + (size_t)ty0 * HID + lane * 4);
        float c, p0 = 0.f;
        c = xs0.x + xd.x + ev0.x; c = (c > 0.f) ? c : 0.2f * c; p0 = fmaf(c, av.x, p0);
        c = xs0.y + xd.y + ev0.y; c = (c > 0.f) ? c : 0.2f * c; p0 = fmaf(c, av.y, p0);
        c = xs0.z + xd.z + ev0.z; c = (c > 0.f) ? c : 0.2f * c; p0 = fmaf(c, av.z, p0);
        c = xs0.w + xd.w + ev0.w; c = (c > 0.f) ? c : 0.2f * c; p0 = fmaf(c, av.w, p0);
        p0 += __shfl_xor(p0, 1);
        p0 += __shfl_xor(p0, 2);
        p0 += __shfl_xor(p0, 4);
        const float ex0 = expf(p0);
        a0 = fmaf(ex0, xs0.x, a0); a1 = fmaf(ex0, xs0.y, a1);
        a2 = fmaf(ex0, xs0.z, a2); a3 = fmaf(ex0, xs0.w, a3);
        sum += ex0;
    }

    const float inv = 1.f / fmaxf(sum, 1e-12f);
    float4 o;
    o.x = a0 * inv; o.y = a1 * inv; o.z = a2 * inv; o.w = a3 * inv;
    *(float4*)(agg + (size_t)node * HID + lane * 4) = o;
}

// ---------------------------------------------------------------------------
// Finalize: per node — agg @ W_out + b_out, FiLM, residual, LayerNorm.
// ---------------------------------------------------------------------------
__global__ __launch_bounds__(128) void finalize(
    const float* __restrict__ agg,
    const float* __restrict__ A,   const float* __restrict__ Wo,
    const float* __restrict__ bo,  const float* __restrict__ film,
    const float* __restrict__ nw_, const float* __restrict__ nb_,
    float* __restrict__ out)
{
    __shared__ float vals[8][HID];
    __shared__ float red[2][2];
    const int t  = threadIdx.x;
    const int nb = blockIdx.x * 8;

    #pragma unroll
    for (int m = 0; m < 8; ++m) {
        const int node = nb + m;
        vals[m][t] = (node < N_NODES) ? agg[(size_t)node * HID + t] : 0.f;
    }
    __syncthreads();

    const float gf  = film[t];
    const float bt  = film[HID + t];
    const float bov = bo[t];
    const float nwv = nw_[t];
    const float nbv = nb_[t];
    const int wave = t >> 6;
    const int lane = t & 63;

    for (int m = 0; m < 8; ++m) {
        const int node = nb + m;
        float acc = 0.f;
        #pragma unroll
        for (int k = 0; k < HID; k += 4) {
            const float4 v4 = *(const float4*)&vals[m][k];   // broadcast
            acc = fmaf(v4.x, Wo[(size_t)(k + 0) * HID + t], acc);
            acc = fmaf(v4.y, Wo[(size_t)(k + 1) * HID + t], acc);
            acc = fmaf(v4.z, Wo[(size_t)(k + 2) * HID + t], acc);
            acc = fmaf(v4.w, Wo[(size_t)(k + 3) * HID + t], acc);
        }
        float v = acc + bov;
        v = v * gf + bt;                                    // FiLM
        const float y = (node < N_NODES ? A[(size_t)node * HID + t] : 0.f) + v;

        float s1 = y, s2 = y * y;
        #pragma unroll
        for (int off = 32; off; off >>= 1) {
            s1 += __shfl_down(s1, off);
            s2 += __shfl_down(s2, off);
        }
        if (lane == 0) { red[wave][0] = s1; red[wave][1] = s2; }
        __syncthreads();
        const float tot1 = red[0][0] + red[1][0];
        const float tot2 = red[0][1] + red[1][1];
        const float mu  = tot1 * (1.f / 128.f);
        const float var = tot2 * (1.f / 128.f) - mu * mu;
        const float rsig = rsqrtf(var + 1e-5f);
        if (node < N_NODES)
            out[(size_t)node * HID + t] = (y - mu) * rsig * nwv + nbv;
        __syncthreads();   // red reused next m
    }
}

// ---------------------------------------------------------------------------
extern "C" void kernel_launch(void* const* d_in, const int* in_sizes, int n_in,
                              void* d_out, int out_size, void* d_ws, size_t ws_size,
                              hipStream_t stream)
{
    const float* node_emb = (const float*)d_in[0];
    const int*   edge_idx = (const int*)  d_in[1];
    const int*   edge_ty  = (const int*)  d_in[2];
    const float* task     = (const float*)d_in[3];
    const float* W_src    = (const float*)d_in[4];
    const float* b_src    = (const float*)d_in[5];
    const float* W_dst    = (const float*)d_in[6];
    const float* b_dst    = (const float*)d_in[7];
    const float* edge_emb = (const float*)d_in[8];
    const float* att      = (const float*)d_in[9];
    const float* W_out    = (const float*)d_in[10];
    const float* b_out    = (const float*)d_in[11];
    const float* norm_w   = (const float*)d_in[12];
    const float* norm_b   = (const float*)d_in[13];
    const float* W_film   = (const float*)d_in[14];
    const float* b_film   = (const float*)d_in[15];
    float* out = (float*)d_out;

    char* ws = (char*)d_ws;
    float* x_src  = (float*)ws;                              ws += (size_t)N_NODES * HID * 4;
    float* x_dst  = (float*)ws;                              ws += (size_t)N_NODES * HID * 4;
    float* agg    = (float*)ws;                              ws += (size_t)N_NODES * HID * 4;
    float* film   = (float*)ws;                              ws += 256 * 4;
    int*   deg    = (int*)ws;                                ws += (size_t)N_NODES * 4;
    int*   rowptr = (int*)ws;                                ws += (size_t)(N_NODES + 1) * 4;
    int*   cursor = (int*)ws;                                ws += (size_t)N_NODES * 4;
    int*   pack   = (int*)ws;                                ws += (size_t)E_EDGES * 4;

    hipMemsetAsync(deg, 0, (size_t)N_NODES * sizeof(int), stream);

    film_kernel<<<1, 256, 0, stream>>>(task, W_film, b_film, film);
    hist_kernel<<<(E_EDGES + 255) / 256, 256, 0, stream>>>(edge_idx, deg);
    gemm_srcdst<<<(N_NODES + 31) / 32, 256, 0, stream>>>(
        node_emb, W_src, b_src, W_dst, b_dst, x_src, x_dst);
    scan_kernel<<<1, 1024, 0, stream>>>(deg, rowptr, cursor);
    scatter_kernel<<<(E_EDGES + 255) / 256, 256, 0, stream>>>(
        edge_idx, edge_ty, cursor, pack);
    gather_agg<<<(N_NODES + 7) / 8, 256, 0, stream>>>(
        rowptr, pack, x_src, x_dst, edge_emb, att, agg);
    finalize<<<(N_NODES + 7) / 8, 128, 0, stream>>>(
        agg, node_emb, W_out, b_out, film, norm_w, norm_b, out);
}

// Round 3
// 412.687 us; speedup vs baseline: 2.8385x; 1.2085x over previous
//
#include <hip/hip_runtime.h>
#include <hip/hip_bf16.h>

#define N_NODES 50000
#define E_EDGES 500000
#define HID 128
#define NHEAD 4
#define HDIM 32

// ---------------------------------------------------------------------------
// FiLM: film[j] = task @ W_film[:,j] + b_film[j]; store gamma-factor and beta
// ---------------------------------------------------------------------------
__global__ __launch_bounds__(256) void film_kernel(
    const float* __restrict__ task, const float* __restrict__ Wf,
    const float* __restrict__ bf, float* __restrict__ film)
{
    __shared__ float tsk[HID];
    const int t = threadIdx.x;
    if (t < HID) tsk[t] = task[t];
    __syncthreads();
    float acc = bf[t];
    #pragma unroll 8
    for (int k = 0; k < HID; ++k)
        acc = fmaf(tsk[k], Wf[k * 256 + t], acc);
    if (t < HID) film[t] = 1.f + 0.5f * tanhf(acc);   // gamma factor
    else         film[t] = acc;                        // beta
}

// ---------------------------------------------------------------------------
// Fused x_src / x_dst GEMM: [32 nodes] x [256 cols (128 src | 128 dst)]
// ---------------------------------------------------------------------------
__global__ __launch_bounds__(256) void gemm_srcdst(
    const float* __restrict__ A,
    const float* __restrict__ Ws, const float* __restrict__ bs,
    const float* __restrict__ Wd, const float* __restrict__ bd,
    float* __restrict__ xs, float* __restrict__ xd)
{
    __shared__ float a_tile[32][HID];
    const int t  = threadIdx.x;
    const int nb = blockIdx.x * 32;

    #pragma unroll
    for (int i = 0; i < 4; ++i) {
        int f  = t + 256 * i;        // float4 index within tile
        int m  = f >> 5;             // node within tile (32 float4 per row)
        int k4 = f & 31;
        int node = nb + m;
        float4 v;
        if (node < N_NODES) v = *(const float4*)(A + (size_t)node * HID + k4 * 4);
        else { v.x = v.y = v.z = v.w = 0.f; }
        *(float4*)&a_tile[m][k4 * 4] = v;
    }
    __syncthreads();

    const int tx = t & 63;
    const int ty = t >> 6;            // wave id (uniform within wave)
    const int m0 = ty * 8;
    const bool is_src = (tx < 32);
    const int cc = (tx & 31) * 4;
    const float* W    = is_src ? Ws : Wd;
    const float* bias = is_src ? bs : bd;
    float*       xout = is_src ? xs : xd;

    float acc[8][4];
    #pragma unroll
    for (int m = 0; m < 8; ++m)
        #pragma unroll
        for (int j = 0; j < 4; ++j) acc[m][j] = 0.f;

    for (int kc = 0; kc < 32; ++kc) {
        const int k0 = kc * 4;
        const float4 w0 = *(const float4*)(W + (size_t)(k0 + 0) * HID + cc);
        const float4 w1 = *(const float4*)(W + (size_t)(k0 + 1) * HID + cc);
        const float4 w2 = *(const float4*)(W + (size_t)(k0 + 2) * HID + cc);
        const float4 w3 = *(const float4*)(W + (size_t)(k0 + 3) * HID + cc);
        #pragma unroll
        for (int m = 0; m < 8; ++m) {
            const float4 av = *(const float4*)&a_tile[m0 + m][k0];
            acc[m][0] = fmaf(av.x, w0.x, acc[m][0]);
            acc[m][1] = fmaf(av.x, w0.y, acc[m][1]);
            acc[m][2] = fmaf(av.x, w0.z, acc[m][2]);
            acc[m][3] = fmaf(av.x, w0.w, acc[m][3]);
            acc[m][0] = fmaf(av.y, w1.x, acc[m][0]);
            acc[m][1] = fmaf(av.y, w1.y, acc[m][1]);
            acc[m][2] = fmaf(av.y, w1.z, acc[m][2]);
            acc[m][3] = fmaf(av.y, w1.w, acc[m][3]);
            acc[m][0] = fmaf(av.z, w2.x, acc[m][0]);
            acc[m][1] = fmaf(av.z, w2.y, acc[m][1]);
            acc[m][2] = fmaf(av.z, w2.z, acc[m][2]);
            acc[m][3] = fmaf(av.z, w2.w, acc[m][3]);
            acc[m][0] = fmaf(av.w, w3.x, acc[m][0]);
            acc[m][1] = fmaf(av.w, w3.y, acc[m][1]);
            acc[m][2] = fmaf(av.w, w3.z, acc[m][2]);
            acc[m][3] = fmaf(av.w, w3.w, acc[m][3]);
        }
    }

    const float4 bv = *(const float4*)(bias + cc);
    #pragma unroll
    for (int m = 0; m < 8; ++m) {
        const int node = nb + m0 + m;
        if (node < N_NODES) {
            float4 o;
            o.x = acc[m][0] + bv.x;
            o.y = acc[m][1] + bv.y;
            o.z = acc[m][2] + bv.z;
            o.w = acc[m][3] + bv.w;
            *(float4*)(xout + (size_t)node * HID + cc) = o;
        }
    }
}

// ---------------------------------------------------------------------------
// CSR build, step 1: in-degree histogram over dst
// ---------------------------------------------------------------------------
__global__ __launch_bounds__(256) void hist_kernel(
    const int* __restrict__ ei, int* __restrict__ deg)
{
    const int e = blockIdx.x * 256 + threadIdx.x;
    if (e < E_EDGES) atomicAdd(&deg[ei[E_EDGES + e]], 1);
}

// ---------------------------------------------------------------------------
// CSR build, step 2: single-block exclusive scan of deg -> rowptr (+cursor)
// ---------------------------------------------------------------------------
__global__ __launch_bounds__(1024) void scan_kernel(
    const int* __restrict__ deg, int* __restrict__ rowptr, int* __restrict__ cursor)
{
    __shared__ int part[1024];
    const int t = threadIdx.x;
    const int CH = (N_NODES + 1023) / 1024;   // 49
    const int base = t * CH;
    int s = 0;
    for (int i = 0; i < CH; ++i) {
        const int idx = base + i;
        if (idx < N_NODES) s += deg[idx];
    }
    part[t] = s;
    __syncthreads();
    for (int off = 1; off < 1024; off <<= 1) {
        const int v = (t >= off) ? part[t - off] : 0;
        __syncthreads();
        part[t] += v;
        __syncthreads();
    }
    int run = part[t] - s;                    // exclusive prefix for this chunk
    for (int i = 0; i < CH; ++i) {
        const int idx = base + i;
        if (idx < N_NODES) {
            rowptr[idx] = run;
            cursor[idx] = run;
            run += deg[idx];
        }
    }
    if (t == 0) rowptr[N_NODES] = E_EDGES;
}

// ---------------------------------------------------------------------------
// CSR build, step 3: scatter packed (src | etype<<16) records into dst bins
// ---------------------------------------------------------------------------
__global__ __launch_bounds__(256) void scatter_kernel(
    const int* __restrict__ ei, const int* __restrict__ et,
    int* __restrict__ cursor, int* __restrict__ pack)
{
    const int e = blockIdx.x * 256 + threadIdx.x;
    if (e < E_EDGES) {
        const int d = ei[E_EDGES + e];
        const int pos = atomicAdd(&cursor[d], 1);
        pack[pos] = ei[e] | (et[e] << 16);    // src < 65536, etype < 8
    }
}

// ---------------------------------------------------------------------------
// Gather-aggregate: one 32-lane group per dst node. Walks in-edges, computes
// ex = exp(logit), accumulates ex*x_src and ex in registers; normalizes and
// writes one 512B row per node. Zero atomics.
// ---------------------------------------------------------------------------
__global__ __launch_bounds__(256) void gather_agg(
    const int* __restrict__ rowptr, const int* __restrict__ pack,
    const float* __restrict__ xsrc, const float* __restrict__ xdst,
    const float* __restrict__ eemb, const float* __restrict__ att,
    float* __restrict__ agg)
{
    const int lane = threadIdx.x & 31;
    const int grp  = threadIdx.x >> 5;
    const int node = blockIdx.x * 8 + grp;
    if (node >= N_NODES) return;

    const float4 av = *(const float4*)(att + lane * 4);
    const float4 xd = *(const float4*)(xdst + (size_t)node * HID + lane * 4);

    float a0 = 0.f, a1 = 0.f, a2 = 0.f, a3 = 0.f, sum = 0.f;
    const int b = rowptr[node];
    const int e = rowptr[node + 1];

    int i = b;
    for (; i + 1 < e; i += 2) {               // 2-wide for load overlap
        const int pk0 = pack[i];
        const int pk1 = pack[i + 1];
        const int s0 = pk0 & 0xFFFF, ty0 = pk0 >> 16;
        const int s1 = pk1 & 0xFFFF, ty1 = pk1 >> 16;
        const float4 xs0 = *(const float4*)(xsrc + (size_t)s0 * HID + lane * 4);
        const float4 ev0 = *(const float4*)(eemb + (size_t)ty0 * HID + lane * 4);
        const float4 xs1 = *(const float4*)(xsrc + (size_t)s1 * HID + lane * 4);
        const float4 ev1 = *(const float4*)(eemb + (size_t)ty1 * HID + lane * 4);
        float c, p0 = 0.f, p1 = 0.f;
        c = xs0.x + xd.x + ev0.x; c = (c > 0.f) ? c : 0.2f * c; p0 = fmaf(c, av.x, p0);
        c = xs0.y + xd.y + ev0.y; c = (c > 0.f) ? c : 0.2f * c; p0 = fmaf(c, av.y, p0);
        c = xs0.z + xd.z + ev0.z; c = (c > 0.f) ? c : 0.2f * c; p0 = fmaf(c, av.z, p0);
        c = xs0.w + xd.w + ev0.w; c = (c > 0.f) ? c : 0.2f * c; p0 = fmaf(c, av.w, p0);
        c = xs1.x + xd.x + ev1.x; c = (c > 0.f) ? c : 0.2f * c; p1 = fmaf(c, av.x, p1);
        c = xs1.y + xd.y + ev1.y; c = (c > 0.f) ? c : 0.2f * c; p1 = fmaf(c, av.y, p1);
        c = xs1.z + xd.z + ev1.z; c = (c > 0.f) ? c : 0.2f * c; p1 = fmaf(c, av.z, p1);
        c = xs1.w + xd.w + ev1.w; c = (c > 0.f) ? c : 0.2f * c; p1 = fmaf(c, av.w, p1);
        p0 += __shfl_xor(p0, 1); p1 += __shfl_xor(p1, 1);
        p0 += __shfl_xor(p0, 2); p1 += __shfl_xor(p1, 2);
        p0 += __shfl_xor(p0, 4); p1 += __shfl_xor(p1, 4);
        const float ex0 = expf(p0);
        const float ex1 = expf(p1);
        a0 = fmaf(ex0, xs0.x, a0); a1 = fmaf(ex0, xs0.y, a1);
        a2 = fmaf(ex0, xs0.z, a2); a3 = fmaf(ex0, xs0.w, a3);
        a0 = fmaf(ex1, xs1.x, a0); a1 = fmaf(ex1, xs1.y, a1);
        a2 = fmaf(ex1, xs1.z, a2); a3 = fmaf(ex1, xs1.w, a3);
        sum += ex0 + ex1;
    }
    if (i < e) {                              // tail
        const int pk0 = pack[i];
        const int s0 = pk0 & 0xFFFF, ty0 = pk0 >> 16;
        const float4 xs0 = *(const float4*)(xsrc + (size_t)s0 * HID + lane * 4);
        const float4 ev0 = *(const float4*)(eemb + (size_t)ty0 * HID + lane * 4);
        float c, p0 = 0.f;
        c = xs0.x + xd.x + ev0.x; c = (c > 0.f) ? c : 0.2f * c; p0 = fmaf(c, av.x, p0);
        c = xs0.y + xd.y + ev0.y; c = (c > 0.f) ? c : 0.2f * c; p0 = fmaf(c, av.y, p0);
        c = xs0.z + xd.z + ev0.z; c = (c > 0.f) ? c : 0.2f * c; p0 = fmaf(c, av.z, p0);
        c = xs0.w + xd.w + ev0.w; c = (c > 0.f) ? c : 0.2f * c; p0 = fmaf(c, av.w, p0);
        p0 += __shfl_xor(p0, 1);
        p0 += __shfl_xor(p0, 2);
        p0 += __shfl_xor(p0, 4);
        const float ex0 = expf(p0);
        a0 = fmaf(ex0, xs0.x, a0); a1 = fmaf(ex0, xs0.y, a1);
        a2 = fmaf(ex0, xs0.z, a2); a3 = fmaf(ex0, xs0.w, a3);
        sum += ex0;
    }

    const float inv = 1.f / fmaxf(sum, 1e-12f);
    float4 o;
    o.x = a0 * inv; o.y = a1 * inv; o.z = a2 * inv; o.w = a3 * inv;
    *(float4*)(agg + (size_t)node * HID + lane * 4) = o;
}

// ---------------------------------------------------------------------------
// Finalize (GEMM-structured): 64-node tile in LDS, 256 threads.
// col-group cg = t&31 (4 cols each), row-group rg = t>>5 (8 nodes each).
// Single barrier after staging; LN via 32-lane shuffles — no LDS round-trip.
// ---------------------------------------------------------------------------
__global__ __launch_bounds__(256) void finalize(
    const float* __restrict__ agg,
    const float* __restrict__ A,   const float* __restrict__ Wo,
    const float* __restrict__ bo,  const float* __restrict__ film,
    const float* __restrict__ nw_, const float* __restrict__ nb_,
    float* __restrict__ out)
{
    __shared__ float a_tile[64][HID];
    const int t  = threadIdx.x;
    const int nb = blockIdx.x * 64;

    #pragma unroll
    for (int i = 0; i < 8; ++i) {
        int f  = t + 256 * i;        // float4 index within tile
        int m  = f >> 5;
        int k4 = f & 31;
        int node = nb + m;
        float4 v;
        if (node < N_NODES) v = *(const float4*)(agg + (size_t)node * HID + k4 * 4);
        else { v.x = v.y = v.z = v.w = 0.f; }
        *(float4*)&a_tile[m][k4 * 4] = v;
    }
    __syncthreads();

    const int cg = t & 31;
    const int rg = t >> 5;            // 8 row-groups of 8 nodes
    const int cc = cg * 4;
    const int m0 = rg * 8;

    float acc[8][4];
    #pragma unroll
    for (int m = 0; m < 8; ++m)
        #pragma unroll
        for (int j = 0; j < 4; ++j) acc[m][j] = 0.f;

    for (int kc = 0; kc < 32; ++kc) {
        const int k0 = kc * 4;
        const float4 w0 = *(const float4*)(Wo + (size_t)(k0 + 0) * HID + cc);
        const float4 w1 = *(const float4*)(Wo + (size_t)(k0 + 1) * HID + cc);
        const float4 w2 = *(const float4*)(Wo + (size_t)(k0 + 2) * HID + cc);
        const float4 w3 = *(const float4*)(Wo + (size_t)(k0 + 3) * HID + cc);
        #pragma unroll
        for (int m = 0; m < 8; ++m) {
            const float4 av = *(const float4*)&a_tile[m0 + m][k0];
            acc[m][0] = fmaf(av.x, w0.x, acc[m][0]);
            acc[m][1] = fmaf(av.x, w0.y, acc[m][1]);
            acc[m][2] = fmaf(av.x, w0.z, acc[m][2]);
            acc[m][3] = fmaf(av.x, w0.w, acc[m][3]);
            acc[m][0] = fmaf(av.y, w1.x, acc[m][0]);
            acc[m][1] = fmaf(av.y, w1.y, acc[m][1]);
            acc[m][2] = fmaf(av.y, w1.z, acc[m][2]);
            acc[m][3] = fmaf(av.y, w1.w, acc[m][3]);
            acc[m][0] = fmaf(av.z, w2.x, acc[m][0]);
            acc[m][1] = fmaf(av.z, w2.y, acc[m][1]);
            acc[m][2] = fmaf(av.z, w2.z, acc[m][2]);
            acc[m][3] = fmaf(av.z, w2.w, acc[m][3]);
            acc[m][0] = fmaf(av.w, w3.x, acc[m][0]);
            acc[m][1] = fmaf(av.w, w3.y, acc[m][1]);
            acc[m][2] = fmaf(av.w, w3.z, acc[m][2]);
            acc[m][3] = fmaf(av.w, w3.w, acc[m][3]);
        }
    }

    const float4 bv  = *(const float4*)(bo   + cc);
    const float4 gfv = *(const float4*)(film + cc);
    const float4 btv = *(const float4*)(film + HID + cc);
    const float4 nwv = *(const float4*)(nw_  + cc);
    const float4 nbv = *(const float4*)(nb_  + cc);

    #pragma unroll
    for (int m = 0; m < 8; ++m) {
        const int node = nb + m0 + m;
        float4 y;
        float4 r;
        if (node < N_NODES) r = *(const float4*)(A + (size_t)node * HID + cc);
        else { r.x = r.y = r.z = r.w = 0.f; }
        y.x = fmaf(acc[m][0] + bv.x, gfv.x, btv.x) + r.x;
        y.y = fmaf(acc[m][1] + bv.y, gfv.y, btv.y) + r.y;
        y.z = fmaf(acc[m][2] + bv.z, gfv.z, btv.z) + r.z;
        y.w = fmaf(acc[m][3] + bv.w, gfv.w, btv.w) + r.w;

        float s1 = y.x + y.y + y.z + y.w;
        float s2 = y.x * y.x + y.y * y.y + y.z * y.z + y.w * y.w;
        #pragma unroll
        for (int off = 1; off < 32; off <<= 1) {
            s1 += __shfl_xor(s1, off);
            s2 += __shfl_xor(s2, off);
        }
        const float mu   = s1 * (1.f / 128.f);
        const float var  = s2 * (1.f / 128.f) - mu * mu;
        const float rsig = rsqrtf(var + 1e-5f);
        if (node < N_NODES) {
            float4 o;
            o.x = (y.x - mu) * rsig * nwv.x + nbv.x;
            o.y = (y.y - mu) * rsig * nwv.y + nbv.y;
            o.z = (y.z - mu) * rsig * nwv.z + nbv.z;
            o.w = (y.w - mu) * rsig * nwv.w + nbv.w;
            *(float4*)(out + (size_t)node * HID + cc) = o;
        }
    }
}

// ---------------------------------------------------------------------------
extern "C" void kernel_launch(void* const* d_in, const int* in_sizes, int n_in,
                              void* d_out, int out_size, void* d_ws, size_t ws_size,
                              hipStream_t stream)
{
    const float* node_emb = (const float*)d_in[0];
    const int*   edge_idx = (const int*)  d_in[1];
    const int*   edge_ty  = (const int*)  d_in[2];
    const float* task     = (const float*)d_in[3];
    const float* W_src    = (const float*)d_in[4];
    const float* b_src    = (const float*)d_in[5];
    const float* W_dst    = (const float*)d_in[6];
    const float* b_dst    = (const float*)d_in[7];
    const float* edge_emb = (const float*)d_in[8];
    const float* att      = (const float*)d_in[9];
    const float* W_out    = (const float*)d_in[10];
    const float* b_out    = (const float*)d_in[11];
    const float* norm_w   = (const float*)d_in[12];
    const float* norm_b   = (const float*)d_in[13];
    const float* W_film   = (const float*)d_in[14];
    const float* b_film   = (const float*)d_in[15];
    float* out = (float*)d_out;

    char* ws = (char*)d_ws;
    float* x_src  = (float*)ws;                              ws += (size_t)N_NODES * HID * 4;
    float* x_dst  = (float*)ws;                              ws += (size_t)N_NODES * HID * 4;
    float* agg    = (float*)ws;                              ws += (size_t)N_NODES * HID * 4;
    float* film   = (float*)ws;                              ws += 256 * 4;
    int*   deg    = (int*)ws;                                ws += (size_t)N_NODES * 4;
    int*   rowptr = (int*)ws;                                ws += (size_t)(N_NODES + 1) * 4;
    int*   cursor = (int*)ws;                                ws += (size_t)N_NODES * 4;
    int*   pack   = (int*)ws;                                ws += (size_t)E_EDGES * 4;

    hipMemsetAsync(deg, 0, (size_t)N_NODES * sizeof(int), stream);

    film_kernel<<<1, 256, 0, stream>>>(task, W_film, b_film, film);
    hist_kernel<<<(E_EDGES + 255) / 256, 256, 0, stream>>>(edge_idx, deg);
    gemm_srcdst<<<(N_NODES + 31) / 32, 256, 0, stream>>>(
        node_emb, W_src, b_src, W_dst, b_dst, x_src, x_dst);
    scan_kernel<<<1, 1024, 0, stream>>>(deg, rowptr, cursor);
    scatter_kernel<<<(E_EDGES + 255) / 256, 256, 0, stream>>>(
        edge_idx, edge_ty, cursor, pack);
    gather_agg<<<(N_NODES + 7) / 8, 256, 0, stream>>>(
        rowptr, pack, x_src, x_dst, edge_emb, att, agg);
    finalize<<<(N_NODES + 63) / 64, 256, 0, stream>>>(
        agg, node_emb, W_out, b_out, film, norm_w, norm_b, out);
}

// Round 4
// 294.864 us; speedup vs baseline: 3.9728x; 1.3996x over previous
//
#include <hip/hip_runtime.h>
#include <hip/hip_bf16.h>

#define N_NODES 50000
#define E_EDGES 500000
#define HID 128
#define NHEAD 4
#define HDIM 32
#define SCAN_BLOCKS ((N_NODES + 255) / 256)   // 196

// ---------------------------------------------------------------------------
// FiLM: film[j] = task @ W_film[:,j] + b_film[j]; store gamma-factor and beta
// ---------------------------------------------------------------------------
__global__ __launch_bounds__(256) void film_kernel(
    const float* __restrict__ task, const float* __restrict__ Wf,
    const float* __restrict__ bf, float* __restrict__ film)
{
    __shared__ float tsk[HID];
    const int t = threadIdx.x;
    if (t < HID) tsk[t] = task[t];
    __syncthreads();
    float acc = bf[t];
    #pragma unroll 8
    for (int k = 0; k < HID; ++k)
        acc = fmaf(tsk[k], Wf[k * 256 + t], acc);
    if (t < HID) film[t] = 1.f + 0.5f * tanhf(acc);   // gamma factor
    else         film[t] = acc;                        // beta
}

// ---------------------------------------------------------------------------
// Fused x_src / x_dst GEMM: [32 nodes] x [256 cols (128 src | 128 dst)]
// ---------------------------------------------------------------------------
__global__ __launch_bounds__(256) void gemm_srcdst(
    const float* __restrict__ A,
    const float* __restrict__ Ws, const float* __restrict__ bs,
    const float* __restrict__ Wd, const float* __restrict__ bd,
    float* __restrict__ xs, float* __restrict__ xd)
{
    __shared__ float a_tile[32][HID];
    const int t  = threadIdx.x;
    const int nb = blockIdx.x * 32;

    #pragma unroll
    for (int i = 0; i < 4; ++i) {
        int f  = t + 256 * i;        // float4 index within tile
        int m  = f >> 5;             // node within tile (32 float4 per row)
        int k4 = f & 31;
        int node = nb + m;
        float4 v;
        if (node < N_NODES) v = *(const float4*)(A + (size_t)node * HID + k4 * 4);
        else { v.x = v.y = v.z = v.w = 0.f; }
        *(float4*)&a_tile[m][k4 * 4] = v;
    }
    __syncthreads();

    const int tx = t & 63;
    const int ty = t >> 6;            // wave id (uniform within wave)
    const int m0 = ty * 8;
    const bool is_src = (tx < 32);
    const int cc = (tx & 31) * 4;
    const float* W    = is_src ? Ws : Wd;
    const float* bias = is_src ? bs : bd;
    float*       xout = is_src ? xs : xd;

    float acc[8][4];
    #pragma unroll
    for (int m = 0; m < 8; ++m)
        #pragma unroll
        for (int j = 0; j < 4; ++j) acc[m][j] = 0.f;

    for (int kc = 0; kc < 32; ++kc) {
        const int k0 = kc * 4;
        const float4 w0 = *(const float4*)(W + (size_t)(k0 + 0) * HID + cc);
        const float4 w1 = *(const float4*)(W + (size_t)(k0 + 1) * HID + cc);
        const float4 w2 = *(const float4*)(W + (size_t)(k0 + 2) * HID + cc);
        const float4 w3 = *(const float4*)(W + (size_t)(k0 + 3) * HID + cc);
        #pragma unroll
        for (int m = 0; m < 8; ++m) {
            const float4 av = *(const float4*)&a_tile[m0 + m][k0];
            acc[m][0] = fmaf(av.x, w0.x, acc[m][0]);
            acc[m][1] = fmaf(av.x, w0.y, acc[m][1]);
            acc[m][2] = fmaf(av.x, w0.z, acc[m][2]);
            acc[m][3] = fmaf(av.x, w0.w, acc[m][3]);
            acc[m][0] = fmaf(av.y, w1.x, acc[m][0]);
            acc[m][1] = fmaf(av.y, w1.y, acc[m][1]);
            acc[m][2] = fmaf(av.y, w1.z, acc[m][2]);
            acc[m][3] = fmaf(av.y, w1.w, acc[m][3]);
            acc[m][0] = fmaf(av.z, w2.x, acc[m][0]);
            acc[m][1] = fmaf(av.z, w2.y, acc[m][1]);
            acc[m][2] = fmaf(av.z, w2.z, acc[m][2]);
            acc[m][3] = fmaf(av.z, w2.w, acc[m][3]);
            acc[m][0] = fmaf(av.w, w3.x, acc[m][0]);
            acc[m][1] = fmaf(av.w, w3.y, acc[m][1]);
            acc[m][2] = fmaf(av.w, w3.z, acc[m][2]);
            acc[m][3] = fmaf(av.w, w3.w, acc[m][3]);
        }
    }

    const float4 bv = *(const float4*)(bias + cc);
    #pragma unroll
    for (int m = 0; m < 8; ++m) {
        const int node = nb + m0 + m;
        if (node < N_NODES) {
            float4 o;
            o.x = acc[m][0] + bv.x;
            o.y = acc[m][1] + bv.y;
            o.z = acc[m][2] + bv.z;
            o.w = acc[m][3] + bv.w;
            *(float4*)(xout + (size_t)node * HID + cc) = o;
        }
    }
}

// ---------------------------------------------------------------------------
// CSR build, step 1: in-degree histogram over dst
// ---------------------------------------------------------------------------
__global__ __launch_bounds__(256) void hist_kernel(
    const int* __restrict__ ei, int* __restrict__ deg)
{
    const int e = blockIdx.x * 256 + threadIdx.x;
    if (e < E_EDGES) atomicAdd(&deg[ei[E_EDGES + e]], 1);
}

// ---------------------------------------------------------------------------
// Two-level scan, step A: per-block (256-wide) reduction of deg
// ---------------------------------------------------------------------------
__global__ __launch_bounds__(256) void reduce_blocks(
    const int* __restrict__ deg, int* __restrict__ blocksum)
{
    __shared__ int ws_[4];
    const int t = threadIdx.x;
    const int i = blockIdx.x * 256 + t;
    int v = (i < N_NODES) ? deg[i] : 0;
    #pragma unroll
    for (int off = 32; off; off >>= 1) v += __shfl_down(v, off);
    if ((t & 63) == 0) ws_[t >> 6] = v;
    __syncthreads();
    if (t == 0) blocksum[blockIdx.x] = ws_[0] + ws_[1] + ws_[2] + ws_[3];
}

// ---------------------------------------------------------------------------
// Two-level scan, step B: single small block scans the 196 block sums
// -> exclusive block offsets
// ---------------------------------------------------------------------------
__global__ __launch_bounds__(256) void scan_blocksums(
    const int* __restrict__ blocksum, int* __restrict__ blockoff,
    int* __restrict__ rowptr)
{
    __shared__ int wtot[4];
    const int t    = threadIdx.x;
    const int lane = t & 63;
    const int w    = t >> 6;
    int v = (t < SCAN_BLOCKS) ? blocksum[t] : 0;
    const int own = v;
    #pragma unroll
    for (int off = 1; off < 64; off <<= 1) {
        const int u = __shfl_up(v, off);
        if (lane >= off) v += u;
    }
    if (lane == 63) wtot[w] = v;
    __syncthreads();
    int woff = 0;
    #pragma unroll
    for (int k = 0; k < 4; ++k) if (k < w) woff += wtot[k];
    if (t < SCAN_BLOCKS) blockoff[t] = woff + v - own;   // exclusive
    if (t == 0) rowptr[N_NODES] = E_EDGES;
}

// ---------------------------------------------------------------------------
// Two-level scan, step C: per-block exclusive scan + block offset
// -> rowptr, cursor
// ---------------------------------------------------------------------------
__global__ __launch_bounds__(256) void scan_within(
    const int* __restrict__ deg, const int* __restrict__ blockoff,
    int* __restrict__ rowptr, int* __restrict__ cursor)
{
    __shared__ int wtot[4];
    const int t    = threadIdx.x;
    const int lane = t & 63;
    const int w    = t >> 6;
    const int i    = blockIdx.x * 256 + t;
    int v = (i < N_NODES) ? deg[i] : 0;
    const int own = v;
    #pragma unroll
    for (int off = 1; off < 64; off <<= 1) {
        const int u = __shfl_up(v, off);
        if (lane >= off) v += u;
    }
    if (lane == 63) wtot[w] = v;
    __syncthreads();
    int woff = blockoff[blockIdx.x];
    #pragma unroll
    for (int k = 0; k < 4; ++k) if (k < w) woff += wtot[k];
    if (i < N_NODES) {
        const int ex = woff + v - own;
        rowptr[i] = ex;
        cursor[i] = ex;
    }
}

// ---------------------------------------------------------------------------
// CSR build, step 3: scatter packed (src | etype<<16) records into dst bins
// ---------------------------------------------------------------------------
__global__ __launch_bounds__(256) void scatter_kernel(
    const int* __restrict__ ei, const int* __restrict__ et,
    int* __restrict__ cursor, int* __restrict__ pack)
{
    const int e = blockIdx.x * 256 + threadIdx.x;
    if (e < E_EDGES) {
        const int d = ei[E_EDGES + e];
        const int pos = atomicAdd(&cursor[d], 1);
        pack[pos] = ei[e] | (et[e] << 16);    // src < 65536, etype < 8
    }
}

// ---------------------------------------------------------------------------
// Gather-aggregate: one 32-lane group per dst node. Walks in-edges, computes
// ex = exp(logit), accumulates ex*x_src and ex in registers; normalizes and
// writes one 512B row per node. Zero atomics.
// ---------------------------------------------------------------------------
__global__ __launch_bounds__(256) void gather_agg(
    const int* __restrict__ rowptr, const int* __restrict__ pack,
    const float* __restrict__ xsrc, const float* __restrict__ xdst,
    const float* __restrict__ eemb, const float* __restrict__ att,
    float* __restrict__ agg)
{
    const int lane = threadIdx.x & 31;
    const int grp  = threadIdx.x >> 5;
    const int node = blockIdx.x * 8 + grp;
    if (node >= N_NODES) return;

    const float4 av = *(const float4*)(att + lane * 4);
    const float4 xd = *(const float4*)(xdst + (size_t)node * HID + lane * 4);

    float a0 = 0.f, a1 = 0.f, a2 = 0.f, a3 = 0.f, sum = 0.f;
    const int b = rowptr[node];
    const int e = rowptr[node + 1];

    int i = b;
    for (; i + 1 < e; i += 2) {               // 2-wide for load overlap
        const int pk0 = pack[i];
        const int pk1 = pack[i + 1];
        const int s0 = pk0 & 0xFFFF, ty0 = pk0 >> 16;
        const int s1 = pk1 & 0xFFFF, ty1 = pk1 >> 16;
        const float4 xs0 = *(const float4*)(xsrc + (size_t)s0 * HID + lane * 4);
        const float4 ev0 = *(const float4*)(eemb + (size_t)ty0 * HID + lane * 4);
        const float4 xs1 = *(const float4*)(xsrc + (size_t)s1 * HID + lane * 4);
        const float4 ev1 = *(const float4*)(eemb + (size_t)ty1 * HID + lane * 4);
        float c, p0 = 0.f, p1 = 0.f;
        c = xs0.x + xd.x + ev0.x; c = (c > 0.f) ? c : 0.2f * c; p0 = fmaf(c, av.x, p0);
        c = xs0.y + xd.y + ev0.y; c = (c > 0.f) ? c : 0.2f * c; p0 = fmaf(c, av.y, p0);
        c = xs0.z + xd.z + ev0.z; c = (c > 0.f) ? c : 0.2f * c; p0 = fmaf(c, av.z, p0);
        c = xs0.w + xd.w + ev0.w; c = (c > 0.f) ? c : 0.2f * c; p0 = fmaf(c, av.w, p0);
        c = xs1.x + xd.x + ev1.x; c = (c > 0.f) ? c : 0.2f * c; p1 = fmaf(c, av.x, p1);
        c = xs1.y + xd.y + ev1.y; c = (c > 0.f) ? c : 0.2f * c; p1 = fmaf(c, av.y, p1);
        c = xs1.z + xd.z + ev1.z; c = (c > 0.f) ? c : 0.2f * c; p1 = fmaf(c, av.z, p1);
        c = xs1.w + xd.w + ev1.w; c = (c > 0.f) ? c : 0.2f * c; p1 = fmaf(c, av.w, p1);
        p0 += __shfl_xor(p0, 1); p1 += __shfl_xor(p1, 1);
        p0 += __shfl_xor(p0, 2); p1 += __shfl_xor(p1, 2);
        p0 += __shfl_xor(p0, 4); p1 += __shfl_xor(p1, 4);
        const float ex0 = expf(p0);
        const float ex1 = expf(p1);
        a0 = fmaf(ex0, xs0.x, a0); a1 = fmaf(ex0, xs0.y, a1);
        a2 = fmaf(ex0, xs0.z, a2); a3 = fmaf(ex0, xs0.w, a3);
        a0 = fmaf(ex1, xs1.x, a0); a1 = fmaf(ex1, xs1.y, a1);
        a2 = fmaf(ex1, xs1.z, a2); a3 = fmaf(ex1, xs1.w, a3);
        sum += ex0 + ex1;
    }
    if (i < e) {                              // tail
        const int pk0 = pack[i];
        const int s0 = pk0 & 0xFFFF, ty0 = pk0 >> 16;
        const float4 xs0 = *(const float4*)(xsrc + (size_t)s0 * HID + lane * 4);
        const float4 ev0 = *(const float4*)(eemb + (size_t)ty0 * HID + lane * 4);
        float c, p0 = 0.f;
        c = xs0.x + xd.x + ev0.x; c = (c > 0.f) ? c : 0.2f * c; p0 = fmaf(c, av.x, p0);
        c = xs0.y + xd.y + ev0.y; c = (c > 0.f) ? c : 0.2f * c; p0 = fmaf(c, av.y, p0);
        c = xs0.z + xd.z + ev0.z; c = (c > 0.f) ? c : 0.2f * c; p0 = fmaf(c, av.z, p0);
        c = xs0.w + xd.w + ev0.w; c = (c > 0.f) ? c : 0.2f * c; p0 = fmaf(c, av.w, p0);
        p0 += __shfl_xor(p0, 1);
        p0 += __shfl_xor(p0, 2);
        p0 += __shfl_xor(p0, 4);
        const float ex0 = expf(p0);
        a0 = fmaf(ex0, xs0.x, a0); a1 = fmaf(ex0, xs0.y, a1);
        a2 = fmaf(ex0, xs0.z, a2); a3 = fmaf(ex0, xs0.w, a3);
        sum += ex0;
    }

    const float inv = 1.f / fmaxf(sum, 1e-12f);
    float4 o;
    o.x = a0 * inv; o.y = a1 * inv; o.z = a2 * inv; o.w = a3 * inv;
    *(float4*)(agg + (size_t)node * HID + lane * 4) = o;
}

// ---------------------------------------------------------------------------
// Finalize (GEMM-structured): 64-node tile in LDS, 256 threads.
// Single barrier after staging; LN via 32-lane shuffles — no LDS round-trip.
// ---------------------------------------------------------------------------
__global__ __launch_bounds__(256) void finalize(
    const float* __restrict__ agg,
    const float* __restrict__ A,   const float* __restrict__ Wo,
    const float* __restrict__ bo,  const float* __restrict__ film,
    const float* __restrict__ nw_, const float* __restrict__ nb_,
    float* __restrict__ out)
{
    __shared__ float a_tile[64][HID];
    const int t  = threadIdx.x;
    const int nb = blockIdx.x * 64;

    #pragma unroll
    for (int i = 0; i < 8; ++i) {
        int f  = t + 256 * i;        // float4 index within tile
        int m  = f >> 5;
        int k4 = f & 31;
        int node = nb + m;
        float4 v;
        if (node < N_NODES) v = *(const float4*)(agg + (size_t)node * HID + k4 * 4);
        else { v.x = v.y = v.z = v.w = 0.f; }
        *(float4*)&a_tile[m][k4 * 4] = v;
    }
    __syncthreads();

    const int cg = t & 31;
    const int rg = t >> 5;            // 8 row-groups of 8 nodes
    const int cc = cg * 4;
    const int m0 = rg * 8;

    float acc[8][4];
    #pragma unroll
    for (int m = 0; m < 8; ++m)
        #pragma unroll
        for (int j = 0; j < 4; ++j) acc[m][j] = 0.f;

    for (int kc = 0; kc < 32; ++kc) {
        const int k0 = kc * 4;
        const float4 w0 = *(const float4*)(Wo + (size_t)(k0 + 0) * HID + cc);
        const float4 w1 = *(const float4*)(Wo + (size_t)(k0 + 1) * HID + cc);
        const float4 w2 = *(const float4*)(Wo + (size_t)(k0 + 2) * HID + cc);
        const float4 w3 = *(const float4*)(Wo + (size_t)(k0 + 3) * HID + cc);
        #pragma unroll
        for (int m = 0; m < 8; ++m) {
            const float4 av = *(const float4*)&a_tile[m0 + m][k0];
            acc[m][0] = fmaf(av.x, w0.x, acc[m][0]);
            acc[m][1] = fmaf(av.x, w0.y, acc[m][1]);
            acc[m][2] = fmaf(av.x, w0.z, acc[m][2]);
            acc[m][3] = fmaf(av.x, w0.w, acc[m][3]);
            acc[m][0] = fmaf(av.y, w1.x, acc[m][0]);
            acc[m][1] = fmaf(av.y, w1.y, acc[m][1]);
            acc[m][2] = fmaf(av.y, w1.z, acc[m][2]);
            acc[m][3] = fmaf(av.y, w1.w, acc[m][3]);
            acc[m][0] = fmaf(av.z, w2.x, acc[m][0]);
            acc[m][1] = fmaf(av.z, w2.y, acc[m][1]);
            acc[m][2] = fmaf(av.z, w2.z, acc[m][2]);
            acc[m][3] = fmaf(av.z, w2.w, acc[m][3]);
            acc[m][0] = fmaf(av.w, w3.x, acc[m][0]);
            acc[m][1] = fmaf(av.w, w3.y, acc[m][1]);
            acc[m][2] = fmaf(av.w, w3.z, acc[m][2]);
            acc[m][3] = fmaf(av.w, w3.w, acc[m][3]);
        }
    }

    const float4 bv  = *(const float4*)(bo   + cc);
    const float4 gfv = *(const float4*)(film + cc);
    const float4 btv = *(const float4*)(film + HID + cc);
    const float4 nwv = *(const float4*)(nw_  + cc);
    const float4 nbv = *(const float4*)(nb_  + cc);

    #pragma unroll
    for (int m = 0; m < 8; ++m) {
        const int node = nb + m0 + m;
        float4 y;
        float4 r;
        if (node < N_NODES) r = *(const float4*)(A + (size_t)node * HID + cc);
        else { r.x = r.y = r.z = r.w = 0.f; }
        y.x = fmaf(acc[m][0] + bv.x, gfv.x, btv.x) + r.x;
        y.y = fmaf(acc[m][1] + bv.y, gfv.y, btv.y) + r.y;
        y.z = fmaf(acc[m][2] + bv.z, gfv.z, btv.z) + r.z;
        y.w = fmaf(acc[m][3] + bv.w, gfv.w, btv.w) + r.w;

        float s1 = y.x + y.y + y.z + y.w;
        float s2 = y.x * y.x + y.y * y.y + y.z * y.z + y.w * y.w;
        #pragma unroll
        for (int off = 1; off < 32; off <<= 1) {
            s1 += __shfl_xor(s1, off);
            s2 += __shfl_xor(s2, off);
        }
        const float mu   = s1 * (1.f / 128.f);
        const float var  = s2 * (1.f / 128.f) - mu * mu;
        const float rsig = rsqrtf(var + 1e-5f);
        if (node < N_NODES) {
            float4 o;
            o.x = (y.x - mu) * rsig * nwv.x + nbv.x;
            o.y = (y.y - mu) * rsig * nwv.y + nbv.y;
            o.z = (y.z - mu) * rsig * nwv.z + nbv.z;
            o.w = (y.w - mu) * rsig * nwv.w + nbv.w;
            *(float4*)(out + (size_t)node * HID + cc) = o;
        }
    }
}

// ---------------------------------------------------------------------------
extern "C" void kernel_launch(void* const* d_in, const int* in_sizes, int n_in,
                              void* d_out, int out_size, void* d_ws, size_t ws_size,
                              hipStream_t stream)
{
    const float* node_emb = (const float*)d_in[0];
    const int*   edge_idx = (const int*)  d_in[1];
    const int*   edge_ty  = (const int*)  d_in[2];
    const float* task     = (const float*)d_in[3];
    const float* W_src    = (const float*)d_in[4];
    const float* b_src    = (const float*)d_in[5];
    const float* W_dst    = (const float*)d_in[6];
    const float* b_dst    = (const float*)d_in[7];
    const float* edge_emb = (const float*)d_in[8];
    const float* att      = (const float*)d_in[9];
    const float* W_out    = (const float*)d_in[10];
    const float* b_out    = (const float*)d_in[11];
    const float* norm_w   = (const float*)d_in[12];
    const float* norm_b   = (const float*)d_in[13];
    const float* W_film   = (const float*)d_in[14];
    const float* b_film   = (const float*)d_in[15];
    float* out = (float*)d_out;

    char* ws = (char*)d_ws;
    float* x_src    = (float*)ws;                            ws += (size_t)N_NODES * HID * 4;
    float* x_dst    = (float*)ws;                            ws += (size_t)N_NODES * HID * 4;
    float* agg      = (float*)ws;                            ws += (size_t)N_NODES * HID * 4;
    float* film     = (float*)ws;                            ws += 256 * 4;
    int*   deg      = (int*)ws;                              ws += (size_t)N_NODES * 4;
    int*   rowptr   = (int*)ws;                              ws += (size_t)(N_NODES + 1) * 4;
    int*   cursor   = (int*)ws;                              ws += (size_t)N_NODES * 4;
    int*   blocksum = (int*)ws;                              ws += 256 * 4;
    int*   blockoff = (int*)ws;                              ws += 256 * 4;
    int*   pack     = (int*)ws;                              ws += (size_t)E_EDGES * 4;

    hipMemsetAsync(deg, 0, (size_t)N_NODES * sizeof(int), stream);

    film_kernel<<<1, 256, 0, stream>>>(task, W_film, b_film, film);
    hist_kernel<<<(E_EDGES + 255) / 256, 256, 0, stream>>>(edge_idx, deg);
    gemm_srcdst<<<(N_NODES + 31) / 32, 256, 0, stream>>>(
        node_emb, W_src, b_src, W_dst, b_dst, x_src, x_dst);
    reduce_blocks<<<SCAN_BLOCKS, 256, 0, stream>>>(deg, blocksum);
    scan_blocksums<<<1, 256, 0, stream>>>(blocksum, blockoff, rowptr);
    scan_within<<<SCAN_BLOCKS, 256, 0, stream>>>(deg, blockoff, rowptr, cursor);
    scatter_kernel<<<(E_EDGES + 255) / 256, 256, 0, stream>>>(
        edge_idx, edge_ty, cursor, pack);
    gather_agg<<<(N_NODES + 7) / 8, 256, 0, stream>>>(
        rowptr, pack, x_src, x_dst, edge_emb, att, agg);
    finalize<<<(N_NODES + 63) / 64, 256, 0, stream>>>(
        agg, node_emb, W_out, b_out, film, norm_w, norm_b, out);
}